// Round 3
// baseline (4014.419 us; speedup 1.0000x reference)
//
#include <hip/hip_runtime.h>

typedef __bf16 bf16x8 __attribute__((ext_vector_type(8)));
typedef float f32x4 __attribute__((ext_vector_type(4)));

#define TSTEPS 7
#define FEAT 60
#define MTILE 128
#define THREADS 512
#define XCHUNKS (MTILE * 15)  // float4 chunks per x step-tile

// ---- preprocessing: transpose + bf16-cast weights into workspace ----
// Ut: [1024][256] bf16, row n = gate-column of U (U is [256][1024] row-major)
__global__ void prep_U_kernel(const float* __restrict__ U, __bf16* __restrict__ Ut) {
    int idx = blockIdx.x * blockDim.x + threadIdx.x;  // 1024*256
    int n = idx >> 8;
    int k = idx & 255;
    Ut[idx] = (__bf16)U[k * 1024 + n];
}

// Wt: [1024][64] bf16, K padded 60->64 with zeros
__global__ void prep_W_kernel(const float* __restrict__ W, __bf16* __restrict__ Wt) {
    int idx = blockIdx.x * blockDim.x + threadIdx.x;  // 1024*64
    int n = idx >> 6;
    int k = idx & 63;
    float v = (k < FEAT) ? W[k * 1024 + n] : 0.0f;
    Wt[idx] = (__bf16)v;
}

__device__ __forceinline__ float sigm(float z) {
    return __builtin_amdgcn_rcpf(1.0f + __expf(-z));
}
// tanh via 1 - 2/(e^{2z}+1): no NaN at |z| large (inf -> 1, 0 -> -1)
__device__ __forceinline__ float tanh_(float z) {
    return 1.0f - 2.0f * __builtin_amdgcn_rcpf(__expf(2.0f * z) + 1.0f);
}

// 512 threads = 8 waves, MTILE=128 batch rows per block, 1 block/CU.
// Wave (wrow, wcol): wrow = wave>>2 picks 64-row half, wcol = wave&3 picks
// 64-unit gate-column group -> per-wave shape identical to the old 4-wave
// kernel, but each block amortizes the 640 KB/step weight stream over 2x rows.
// 512-thread block structurally caps VGPR at 256 (2 waves/SIMD) WITHOUT a
// min-waves launch-bound (round 1's (256,2) forced 128 VGPR -> 3.5 GB spill).
//
// Register diet vs round 0: kf-outer accumulation acc[4 gates][4 mt] (64 regs)
// with A-fragments streamed from LDS per kf — no resident a[4][10] (160 regs),
// no iv/pg temps (all gates live simultaneously), bias folded into acc init.
//
// h double-buffered in LDS (compute writes h_new straight to the other buffer
// — no read/write race, no h barrier). x single-buffered; next step's x tile
// prefetched into registers during compute (T14 split), written to LDS in a
// tiny barrier-protected phase.
__global__ __launch_bounds__(THREADS)
void lstm_kernel(const float* __restrict__ x, const __bf16* __restrict__ Ut,
                 const __bf16* __restrict__ Wt, const float* __restrict__ bias,
                 float* __restrict__ out, int B) {
    // h: [2][m][264] bf16 (stride 264 -> 16B-aligned rows, 4-bank row offset)
    __shared__ __align__(16) __bf16 h_lds[2][MTILE][264];  // 135168 B
    // x: [m][72] bf16 (pad 60->64 zeroed, stride 72 -> 9-chunk superbank step)
    __shared__ __align__(16) __bf16 x_lds[MTILE][72];      // 18432 B -> 153600 total

    const int tid = threadIdx.x;
    const int wave = tid >> 6;
    const int lane = tid & 63;
    const int quad = lane >> 4;
    const int l16 = lane & 15;
    const int wrow = (wave >> 2) * 64;  // 0 or 64: row half
    const int wcol = (wave & 3) * 64;   // unit group base
    const int r0 = blockIdx.x * MTILE;

    // zero x K-pad cols 60..63 once (staging never writes them; must be 0)
    x_lds[tid >> 2][FEAT + (tid & 3)] = (__bf16)0.0f;

    // stage x[:,0,:] (float4-vectorized; row byte offsets are 16B-aligned)
    for (int i = tid; i < XCHUNKS; i += THREADS) {
        int m = i / 15;
        int q = i - m * 15;
        const float4 v = *(const float4*)&x[(size_t)(r0 + m) * (TSTEPS * FEAT) + q * 4];
        __bf16* dst = &x_lds[m][q * 4];
        dst[0] = (__bf16)v.x;
        dst[1] = (__bf16)v.y;
        dst[2] = (__bf16)v.z;
        dst[3] = (__bf16)v.w;
    }

    // c state: [uc][mt][reg] in C/D fragment layout (output-stationary)
    float c_reg[4][4][4];
#pragma unroll
    for (int uc = 0; uc < 4; ++uc)
#pragma unroll
        for (int mt = 0; mt < 4; ++mt)
#pragma unroll
            for (int r = 0; r < 4; ++r) c_reg[uc][mt][r] = 0.0f;

    // bias for this lane's columns (folded into acc init each step)
    float bvals[4][4];
#pragma unroll
    for (int uc = 0; uc < 4; ++uc)
#pragma unroll
        for (int g = 0; g < 4; ++g)
            bvals[uc][g] = bias[g * 256 + wcol + uc * 16 + l16];

    __syncthreads();  // x_lds[t=0] ready

    const size_t HN = (size_t)B * 256;

#pragma unroll 1  // keep code size sane; per-step body is already huge
    for (int t = 0; t < TSTEPS; ++t) {
        const int rb = t & 1;  // h read buffer; writes go to rb^1
        const int wb = rb ^ 1;

        // ---- early-issue next x tile into registers (latency hides under
        // the ~25K-cycle compute phase; written to LDS after the barrier) ----
        float4 xr[4];
        if (t + 1 < TSTEPS) {
#pragma unroll
            for (int k = 0; k < 4; ++k) {
                int i = tid + k * THREADS;
                if (i < XCHUNKS) {
                    int m = i / 15;
                    int q = i - m * 15;
                    xr[k] = *(const float4*)&x[((size_t)(r0 + m) * TSTEPS + (t + 1)) * FEAT + q * 4];
                }
            }
        }

        // ---- x A-fragments: only 8, hoisted once per step (reused by all uc) ----
        bf16x8 ax[4][2];
#pragma unroll
        for (int mt = 0; mt < 4; ++mt) {
#pragma unroll
            for (int kx = 0; kx < 2; ++kx)
                ax[mt][kx] = *(const bf16x8*)&x_lds[wrow + mt * 16 + l16][kx * 32 + quad * 8];
        }

#pragma unroll
        for (int uc = 0; uc < 4; ++uc) {
            const int ncol = wcol + uc * 16 + l16;
            const __bf16* uBase = Ut + (size_t)ncol * 256;  // + g*65536 per gate
            const __bf16* wBase = Wt + (size_t)ncol * 64;   // + g*16384 per gate

            // acc[gate][mt], init to bias (all 4 r-slots share col ncol)
            f32x4 acc[4][4];
#pragma unroll
            for (int g = 0; g < 4; ++g) {
                const float bv = bvals[uc][g];
#pragma unroll
                for (int mt = 0; mt < 4; ++mt) acc[g][mt] = (f32x4){bv, bv, bv, bv};
            }

            // ---- h @ U part: kf-outer, A streamed from LDS, 16 indep chains ----
            if (t > 0) {
#pragma unroll
                for (int kf = 0; kf < 8; ++kf) {
                    const int ko = kf * 32 + quad * 8;
                    bf16x8 b0 = *(const bf16x8*)(uBase + 0 * 65536 + ko);
                    bf16x8 b1 = *(const bf16x8*)(uBase + 1 * 65536 + ko);
                    bf16x8 b2 = *(const bf16x8*)(uBase + 2 * 65536 + ko);
                    bf16x8 b3 = *(const bf16x8*)(uBase + 3 * 65536 + ko);
#pragma unroll
                    for (int mt = 0; mt < 4; ++mt) {
                        bf16x8 a = *(const bf16x8*)&h_lds[rb][wrow + mt * 16 + l16][ko];
                        acc[0][mt] = __builtin_amdgcn_mfma_f32_16x16x32_bf16(a, b0, acc[0][mt], 0, 0, 0);
                        acc[1][mt] = __builtin_amdgcn_mfma_f32_16x16x32_bf16(a, b1, acc[1][mt], 0, 0, 0);
                        acc[2][mt] = __builtin_amdgcn_mfma_f32_16x16x32_bf16(a, b2, acc[2][mt], 0, 0, 0);
                        acc[3][mt] = __builtin_amdgcn_mfma_f32_16x16x32_bf16(a, b3, acc[3][mt], 0, 0, 0);
                    }
                }
            }
            // ---- x @ W part (K = 64) using hoisted ax ----
#pragma unroll
            for (int kx = 0; kx < 2; ++kx) {
                const int ko = kx * 32 + quad * 8;
                bf16x8 b0 = *(const bf16x8*)(wBase + 0 * 16384 + ko);
                bf16x8 b1 = *(const bf16x8*)(wBase + 1 * 16384 + ko);
                bf16x8 b2 = *(const bf16x8*)(wBase + 2 * 16384 + ko);
                bf16x8 b3 = *(const bf16x8*)(wBase + 3 * 16384 + ko);
#pragma unroll
                for (int mt = 0; mt < 4; ++mt) {
                    acc[0][mt] = __builtin_amdgcn_mfma_f32_16x16x32_bf16(ax[mt][kx], b0, acc[0][mt], 0, 0, 0);
                    acc[1][mt] = __builtin_amdgcn_mfma_f32_16x16x32_bf16(ax[mt][kx], b1, acc[1][mt], 0, 0, 0);
                    acc[2][mt] = __builtin_amdgcn_mfma_f32_16x16x32_bf16(ax[mt][kx], b2, acc[2][mt], 0, 0, 0);
                    acc[3][mt] = __builtin_amdgcn_mfma_f32_16x16x32_bf16(ax[mt][kx], b3, acc[3][mt], 0, 0, 0);
                }
            }

            // ---- nonlinearities: all 4 gates live -> no temps; write h_new
            // straight to the other h buffer (race-free) ----
#pragma unroll
            for (int mt = 0; mt < 4; ++mt) {
#pragma unroll
                for (int r = 0; r < 4; ++r) {
                    float iv = sigm(acc[0][mt][r]);
                    float fv = sigm(acc[1][mt][r]);
                    float gv = tanh_(acc[2][mt][r]);
                    float ov = sigm(acc[3][mt][r]);
                    float cc = fv * c_reg[uc][mt][r] + iv * gv;
                    c_reg[uc][mt][r] = cc;
                    float hv = ov * tanh_(cc);
                    const int row = wrow + mt * 16 + quad * 4 + r;
                    h_lds[wb][row][ncol] = (__bf16)hv;
                    if (t == TSTEPS - 1) {
                        size_t mg = (size_t)(r0 + row);
                        out[mg * 256 + ncol] = hv;          // last_h
                        out[HN + mg * 256 + ncol] = hv;     // h
                        out[2 * HN + mg * 256 + ncol] = cc; // c
                    }
                }
            }
        }

        // ---- x write phase (tiny): only needed if there is a next step ----
        if (t + 1 < TSTEPS) {
            __syncthreads();  // all x_lds reads of step t done (ax was hoisted)
#pragma unroll
            for (int k = 0; k < 4; ++k) {
                int i = tid + k * THREADS;
                if (i < XCHUNKS) {
                    int m = i / 15;
                    int q = i - m * 15;
                    __bf16* dst = &x_lds[m][q * 4];
                    dst[0] = (__bf16)xr[k].x;
                    dst[1] = (__bf16)xr[k].y;
                    dst[2] = (__bf16)xr[k].z;
                    dst[3] = (__bf16)xr[k].w;
                }
            }
            __syncthreads();  // new x tile + h[wb] visible for step t+1
        }
    }
}

extern "C" void kernel_launch(void* const* d_in, const int* in_sizes, int n_in,
                              void* d_out, int out_size, void* d_ws, size_t ws_size,
                              hipStream_t stream) {
    const float* x = (const float*)d_in[0];
    const float* W = (const float*)d_in[1];
    const float* U = (const float*)d_in[2];
    const float* b = (const float*)d_in[3];
    float* out = (float*)d_out;

    const int B = in_sizes[0] / (TSTEPS * FEAT);

    __bf16* Ut = (__bf16*)d_ws;                              // 1024*256*2 = 512KB
    __bf16* Wt = (__bf16*)((char*)d_ws + 1024 * 256 * 2);    // 1024*64*2  = 128KB

    prep_U_kernel<<<1024, 256, 0, stream>>>(U, Ut);
    prep_W_kernel<<<256, 256, 0, stream>>>(W, Wt);
    lstm_kernel<<<B / MTILE, THREADS, 0, stream>>>(x, Ut, Wt, b, out, B);
}